// Round 4
// baseline (223.281 us; speedup 1.0000x reference)
//
#include <hip/hip_runtime.h>
#include <hip/hip_cooperative_groups.h>

// SimCLR fused pipeline, round 13.
// Change vs r12: gemm1 + BN + gemm2 fused into ONE cooperative kernel.
//   r12 evidence: sim fixed (~32us); remaining ~110us dominated by the
//   gemm1->Y(16.8MB fp32 HBM)->gemm2 round-trip + kernel boundary + 512x
//   replicated BN prologue. BN batch-stats were the only reason for the split.
//   Fused: block owns 16 rows; phase1 MFMA -> Y tile in LDS (padded [16][516])
//   + col-sum atomics; grid.sync(); phase2 BN-finalize (agent-scope loads) +
//   relu + gemm2 K-loop with A from LDS. Y never touches HBM; h read once.
//   Fallback: if hipLaunchCooperativeKernel errors, launch r12's gemm1+gemm2.
// sim_mfma, convert_w, row_finalize identical to r12.

#define NB   4096
#define DIN  192
#define DHID 512
#define DOUT 128
#define N2   8192   // 2*NB
#define NSPLIT 32   // sim col-splits; 256 cols per block
#define SIM_ITERS 16

typedef short short8 __attribute__((ext_vector_type(8)));   // 8 bf16 (4 VGPRs)
typedef float floatx4 __attribute__((ext_vector_type(4)));  // MFMA C/D frag

__device__ inline float fast_exp2(float x) {
#if __has_builtin(__builtin_amdgcn_exp2f)
    return __builtin_amdgcn_exp2f(x);
#else
    return exp2f(x);
#endif
}

__device__ inline unsigned short bf16_rne(float x) {
    unsigned int u = __float_as_uint(x);
    return (unsigned short)((u + 0x7fffu + ((u >> 16) & 1u)) >> 16);
}

// ---------------- convert W1, W2 -> bf16 ------------------------------------
__global__ __launch_bounds__(256) void convert_w(
    const float* __restrict__ W1, const float* __restrict__ W2,
    unsigned short* __restrict__ W1b, unsigned short* __restrict__ W2b)
{
    const int NW1 = DHID * DIN / 4;   // 24576 float4
    const int NW2 = DOUT * DHID / 4;  // 16384 float4
    int id = blockIdx.x * 256 + threadIdx.x;
    const float* src; unsigned short* dst; int off;
    if (id < NW1)            { src = W1; dst = W1b; off = id; }
    else if (id < NW1 + NW2) { src = W2; dst = W2b; off = id - NW1; }
    else return;
    float4 x = ((const float4*)src)[off];
    unsigned int p0 = bf16_rne(x.x) | ((unsigned int)bf16_rne(x.y) << 16);
    unsigned int p1 = bf16_rne(x.z) | ((unsigned int)bf16_rne(x.w) << 16);
    ((uint2*)dst)[off] = make_uint2(p0, p1);
}

#define ZSCALE 1.6986436f   // sqrt(2*log2(e)); Zb = z*ZSCALE so dot = exp2 arg

// ---- FUSED head: y = h@W1^T+b1 -> BN(batch stats) -> relu -> @W2^T+b2 -> L2
// Cooperative, grid 512 x 256 thr (exactly 2 blocks/CU on 256 CUs).
// Block = 16 rows. Phase1: wave w computes cols w*128..+127 (8 nt), K=192;
// Y tile -> LDS [16][516] (pad: 516 = 4 mod 32 banks); col sums -> atomics.
// grid.sync. Phase2: BN finalize from global sums (agent-scope loads), then
// r12-gemm2 body with A sourced from LDS ytile.
__global__ __launch_bounds__(256, 2) void fused_head(
    const float* __restrict__ h1, const float* __restrict__ h2,
    const unsigned short* __restrict__ W1b, const float* __restrict__ b1,
    const unsigned short* __restrict__ W2b,
    float* __restrict__ psumc, float* __restrict__ psqc,
    const float* __restrict__ gamma, const float* __restrict__ beta,
    const float* __restrict__ b2,
    unsigned short* __restrict__ Zb, float* __restrict__ outz)
{
    __shared__ float ytile[16][516];
    __shared__ float sc_sh[DHID], sh_sh[DHID];
    __shared__ float sq_lds[4][16];

    const int t = threadIdx.x;
    const int wave = t >> 6, lane = t & 63;
    const int quad = lane >> 4, l15 = lane & 15;
    const int r0 = blockIdx.x * 16;
    const int v  = (r0 >= NB);

    // ---------------- phase 1: 16 rows of Y, col-sum atomics ----------------
    {
        short8 a1[6];
        {
            const int row = r0 + l15;
            const float* hsrc = (row < NB) ? (h1 + (size_t)row * DIN)
                                           : (h2 + (size_t)(row - NB) * DIN);
            #pragma unroll
            for (int kc = 0; kc < 6; ++kc) {
                const float4* p = (const float4*)(hsrc + kc * 32 + quad * 8);
                float4 x0 = p[0], x1 = p[1];
                float xs[8] = {x0.x,x0.y,x0.z,x0.w,x1.x,x1.y,x1.z,x1.w};
                #pragma unroll
                for (int j = 0; j < 8; ++j) a1[kc][j] = (short)bf16_rne(xs[j]);
            }
        }
        #pragma unroll
        for (int nt = 0; nt < 8; ++nt) {
            const int col = wave * 128 + nt * 16 + l15;
            const short8* bptr = (const short8*)(W1b + (size_t)col * DIN + quad * 8);
            floatx4 acc = {0.f, 0.f, 0.f, 0.f};
            #pragma unroll
            for (int kc = 0; kc < 6; ++kc)
                acc = __builtin_amdgcn_mfma_f32_16x16x32_bf16(a1[kc], bptr[kc * 4], acc, 0, 0, 0);
            const float bias = b1[col];
            float cs = 0.f, cq = 0.f;
            #pragma unroll
            for (int reg = 0; reg < 4; ++reg) {
                float y = acc[reg] + bias;
                ytile[quad * 4 + reg][col] = y;
                cs += y; cq += y * y;
            }
            cs += __shfl_xor(cs, 16); cs += __shfl_xor(cs, 32);
            cq += __shfl_xor(cq, 16); cq += __shfl_xor(cq, 32);
            if (quad == 0) {
                atomicAdd(psumc + v * DHID + col, cs);
                atomicAdd(psqc  + v * DHID + col, cq);
            }
        }
    }
    __threadfence();
    cooperative_groups::this_grid().sync();

    // ---------------- phase 2: BN finalize + relu + gemm2 + L2 norm ---------
    for (int c = t; c < DHID; c += 256) {
        float sm = __hip_atomic_load(psumc + v * DHID + c, __ATOMIC_RELAXED, __HIP_MEMORY_SCOPE_AGENT);
        float sq = __hip_atomic_load(psqc  + v * DHID + c, __ATOMIC_RELAXED, __HIP_MEMORY_SCOPE_AGENT);
        float mean = sm * (1.0f / NB);
        float var  = sq * (1.0f / NB) - mean * mean;
        float rstd = rsqrtf(var + 1e-5f);
        float scv = gamma[c] * rstd;
        sc_sh[c] = scv;
        sh_sh[c] = beta[c] - mean * scv;
    }
    __syncthreads();

    floatx4 acc2[2] = {{0.f,0.f,0.f,0.f},{0.f,0.f,0.f,0.f}};
    for (int kc = 0; kc < 16; ++kc) {
        const int k = kc * 32 + quad * 8;
        float4 y0 = *(const float4*)&ytile[l15][k];
        float4 y1 = *(const float4*)&ytile[l15][k + 4];
        float4 s0 = *(const float4*)&sc_sh[k], s1 = *(const float4*)&sc_sh[k + 4];
        float4 h0 = *(const float4*)&sh_sh[k], h1v = *(const float4*)&sh_sh[k + 4];
        float xs[8];
        xs[0] = fmaxf(y0.x * s0.x + h0.x, 0.f);
        xs[1] = fmaxf(y0.y * s0.y + h0.y, 0.f);
        xs[2] = fmaxf(y0.z * s0.z + h0.z, 0.f);
        xs[3] = fmaxf(y0.w * s0.w + h0.w, 0.f);
        xs[4] = fmaxf(y1.x * s1.x + h1v.x, 0.f);
        xs[5] = fmaxf(y1.y * s1.y + h1v.y, 0.f);
        xs[6] = fmaxf(y1.z * s1.z + h1v.z, 0.f);
        xs[7] = fmaxf(y1.w * s1.w + h1v.w, 0.f);
        short8 a;
        #pragma unroll
        for (int j = 0; j < 8; ++j) a[j] = (short)bf16_rne(xs[j]);
        #pragma unroll
        for (int nt = 0; nt < 2; ++nt) {
            const int col = wave * 32 + nt * 16 + l15;
            short8 b = *(const short8*)(W2b + (size_t)col * DHID + k);
            acc2[nt] = __builtin_amdgcn_mfma_f32_16x16x32_bf16(a, b, acc2[nt], 0, 0, 0);
        }
    }
    float bias2[2];
    #pragma unroll
    for (int nt = 0; nt < 2; ++nt) bias2[nt] = b2[wave * 32 + nt * 16 + l15];

    float zv[4][2];
    #pragma unroll
    for (int reg = 0; reg < 4; ++reg) {
        float sq = 0.f;
        #pragma unroll
        for (int nt = 0; nt < 2; ++nt) {
            zv[reg][nt] = acc2[nt][reg] + bias2[nt];
            sq += zv[reg][nt] * zv[reg][nt];
        }
        sq += __shfl_xor(sq, 1); sq += __shfl_xor(sq, 2);
        sq += __shfl_xor(sq, 4); sq += __shfl_xor(sq, 8);
        if (l15 == 0) sq_lds[wave][quad * 4 + reg] = sq;
    }
    __syncthreads();
    #pragma unroll
    for (int reg = 0; reg < 4; ++reg) {
        float tot = sq_lds[0][quad * 4 + reg] + sq_lds[1][quad * 4 + reg]
                  + sq_lds[2][quad * 4 + reg] + sq_lds[3][quad * 4 + reg];
        float inv = 1.0f / fmaxf(sqrtf(tot), 1e-12f);
        const int row = r0 + quad * 4 + reg;
        const size_t ob = (size_t)row * DOUT;
        #pragma unroll
        for (int nt = 0; nt < 2; ++nt) {
            const int col = wave * 32 + nt * 16 + l15;
            float z = zv[reg][nt] * inv;
            outz[ob + col] = z;
            Zb[ob + col] = bf16_rne(z * ZSCALE);
        }
    }
}

// ------- FALLBACK GEMM1 (r12): Y = [h1;h2] @ W1^T + b1, fused BN col-sums --
__global__ __launch_bounds__(256) void gemm1_mfma(
    const float* __restrict__ h1, const float* __restrict__ h2,
    const unsigned short* __restrict__ W1b, const float* __restrict__ b1,
    float* __restrict__ Y, float* __restrict__ psumc, float* __restrict__ psqc)
{
    const int t = threadIdx.x;
    const int wave = t >> 6, lane = t & 63;
    const int quad = lane >> 4, l15 = lane & 15;
    const int mb = blockIdx.x;
    const int m0 = mb * 128 + wave * 32;
    const int n0 = blockIdx.y * 64;
    const int v  = (mb >= 32);

    short8 a[2][6];
    #pragma unroll
    for (int mt = 0; mt < 2; ++mt) {
        int row = m0 + mt * 16 + l15;
        const float* hsrc = (row < NB) ? (h1 + (size_t)row * DIN)
                                       : (h2 + (size_t)(row - NB) * DIN);
        #pragma unroll
        for (int kc = 0; kc < 6; ++kc) {
            const float4* p = (const float4*)(hsrc + kc * 32 + quad * 8);
            float4 x0 = p[0], x1 = p[1];
            float xs[8] = {x0.x,x0.y,x0.z,x0.w,x1.x,x1.y,x1.z,x1.w};
            #pragma unroll
            for (int j = 0; j < 8; ++j) a[mt][kc][j] = (short)bf16_rne(xs[j]);
        }
    }

    #pragma unroll
    for (int nt = 0; nt < 4; ++nt) {
        const int col = n0 + nt * 16 + l15;
        const short8* bptr = (const short8*)(W1b + (size_t)col * DIN + quad * 8);
        short8 b[6];
        #pragma unroll
        for (int kc = 0; kc < 6; ++kc) b[kc] = bptr[kc * 4];
        floatx4 acc[2] = {{0.f,0.f,0.f,0.f},{0.f,0.f,0.f,0.f}};
        #pragma unroll
        for (int kc = 0; kc < 6; ++kc)
            #pragma unroll
            for (int mt = 0; mt < 2; ++mt)
                acc[mt] = __builtin_amdgcn_mfma_f32_16x16x32_bf16(a[mt][kc], b[kc], acc[mt], 0,0,0);
        const float bias = b1[col];
        float cs = 0.f, cq = 0.f;
        #pragma unroll
        for (int mt = 0; mt < 2; ++mt)
            #pragma unroll
            for (int reg = 0; reg < 4; ++reg) {
                float y = acc[mt][reg] + bias;
                int row = m0 + mt * 16 + quad * 4 + reg;
                Y[(size_t)row * DHID + col] = y;
                cs += y; cq += y * y;
            }
        cs += __shfl_xor(cs, 16); cs += __shfl_xor(cs, 32);
        cq += __shfl_xor(cq, 16); cq += __shfl_xor(cq, 32);
        if (quad == 0) {
            atomicAdd(psumc + v * DHID + col, cs);
            atomicAdd(psqc  + v * DHID + col, cq);
        }
    }
}

// ---- FALLBACK GEMM2 (r12): z = relu(bn(Y)) @ W2^T + b2, L2-norm -----------
__global__ __launch_bounds__(256) void gemm2_mfma(
    const float* __restrict__ Y, const unsigned short* __restrict__ W2b,
    const float* __restrict__ psumc, const float* __restrict__ psqc,
    const float* __restrict__ gamma, const float* __restrict__ beta,
    const float* __restrict__ b2,
    unsigned short* __restrict__ Zb, float* __restrict__ outz)
{
    __shared__ float sc_sh[DHID], sh_sh[DHID];
    __shared__ float sq_lds[4][16];
    const int t = threadIdx.x;
    const int wave = t >> 6, lane = t & 63;
    const int quad = lane >> 4, l15 = lane & 15;
    const int mtbase = blockIdx.x * 16;
    const int v = (mtbase >= NB);

    for (int c = t; c < DHID; c += 256) {
        float mean = psumc[v * DHID + c] * (1.0f / NB);
        float var  = psqc [v * DHID + c] * (1.0f / NB) - mean * mean;
        float rstd = rsqrtf(var + 1e-5f);
        float scv = gamma[c] * rstd;
        sc_sh[c] = scv;
        sh_sh[c] = beta[c] - mean * scv;
    }
    __syncthreads();

    const float* yrow = Y + (size_t)(mtbase + l15) * DHID;
    floatx4 acc[2] = {{0.f,0.f,0.f,0.f},{0.f,0.f,0.f,0.f}};
    for (int kc = 0; kc < 16; ++kc) {
        const int k = kc * 32 + quad * 8;
        float4 y0 = *(const float4*)(yrow + k);
        float4 y1 = *(const float4*)(yrow + k + 4);
        float4 s0 = *(const float4*)&sc_sh[k], s1 = *(const float4*)&sc_sh[k + 4];
        float4 h0 = *(const float4*)&sh_sh[k], h1v = *(const float4*)&sh_sh[k + 4];
        float xs[8];
        xs[0] = fmaxf(y0.x * s0.x + h0.x, 0.f);
        xs[1] = fmaxf(y0.y * s0.y + h0.y, 0.f);
        xs[2] = fmaxf(y0.z * s0.z + h0.z, 0.f);
        xs[3] = fmaxf(y0.w * s0.w + h0.w, 0.f);
        xs[4] = fmaxf(y1.x * s1.x + h1v.x, 0.f);
        xs[5] = fmaxf(y1.y * s1.y + h1v.y, 0.f);
        xs[6] = fmaxf(y1.z * s1.z + h1v.z, 0.f);
        xs[7] = fmaxf(y1.w * s1.w + h1v.w, 0.f);
        short8 a;
        #pragma unroll
        for (int j = 0; j < 8; ++j) a[j] = (short)bf16_rne(xs[j]);
        #pragma unroll
        for (int nt = 0; nt < 2; ++nt) {
            const int col = wave * 32 + nt * 16 + l15;
            short8 b = *(const short8*)(W2b + (size_t)col * DHID + k);
            acc[nt] = __builtin_amdgcn_mfma_f32_16x16x32_bf16(a, b, acc[nt], 0,0,0);
        }
    }
    float bias[2];
    #pragma unroll
    for (int nt = 0; nt < 2; ++nt) bias[nt] = b2[wave * 32 + nt * 16 + l15];

    float zv[4][2];
    #pragma unroll
    for (int reg = 0; reg < 4; ++reg) {
        float sq = 0.f;
        #pragma unroll
        for (int nt = 0; nt < 2; ++nt) {
            zv[reg][nt] = acc[nt][reg] + bias[nt];
            sq += zv[reg][nt] * zv[reg][nt];
        }
        sq += __shfl_xor(sq, 1); sq += __shfl_xor(sq, 2);
        sq += __shfl_xor(sq, 4); sq += __shfl_xor(sq, 8);
        if (l15 == 0) sq_lds[wave][quad * 4 + reg] = sq;
    }
    __syncthreads();
    #pragma unroll
    for (int reg = 0; reg < 4; ++reg) {
        float tot = sq_lds[0][quad * 4 + reg] + sq_lds[1][quad * 4 + reg]
                  + sq_lds[2][quad * 4 + reg] + sq_lds[3][quad * 4 + reg];
        float inv = 1.0f / fmaxf(sqrtf(tot), 1e-12f);
        const int row = mtbase + quad * 4 + reg;
        const size_t ob = (size_t)row * DOUT;
        #pragma unroll
        for (int nt = 0; nt < 2; ++nt) {
            const int col = wave * 32 + nt * 16 + l15;
            float z = zv[reg][nt] * inv;
            outz[ob + col] = z;
            Zb[ob + col] = bf16_rne(z * ZSCALE);
        }
    }
}

// ---- sim: psum_row = sum_cols exp2(Zb . Zb^T) (r12, unchanged) ------------
__global__ __launch_bounds__(256, 2) void sim_mfma(
    const unsigned short* __restrict__ Zb, float* __restrict__ psum)
{
    __shared__ unsigned char bsh[65536];   // 256 rows x 256 B, swizzled
    const int t = threadIdx.x;
    const int wave = t >> 6, lane = t & 63;
    const int quad = lane >> 4, l15 = lane & 15;
    const int mbase = blockIdx.x * 128 + wave * 32;   // 32 rows per wave
    const int cs = blockIdx.y;                        // 0..NSPLIT-1
    const int cbase = cs * (N2 / NSPLIT);             // 256-col slice

    {
        const uint4* src = (const uint4*)(Zb + (size_t)cbase * DOUT);
        #pragma unroll
        for (int k = 0; k < 16; ++k) {
            int idx = t + k * 256;            // uint4 index 0..4095
            uint4 vv = src[idx];
            int row  = idx >> 4;              // slice row 0..255
            int slot = idx & 15;              // 16B slot within row
            *(uint4*)(bsh + row * 256 + ((slot ^ (row & 15)) << 4)) = vv;
        }
    }

    short8 a[2][4];
    #pragma unroll
    for (int at = 0; at < 2; ++at) {
        const short8* zra = (const short8*)(Zb + (size_t)(mbase + at * 16 + l15) * DOUT + quad * 8);
        #pragma unroll
        for (int kc = 0; kc < 4; ++kc) a[at][kc] = zra[kc * 4];
    }

    float rs[2][4];
    #pragma unroll
    for (int at = 0; at < 2; ++at)
        #pragma unroll
        for (int r = 0; r < 4; ++r) rs[at][r] = 0.f;

    __syncthreads();   // B slice staged

    #pragma unroll 1
    for (int nt = 0; nt < SIM_ITERS; ++nt) {
        const int crow = nt * 16 + l15;
        short8 b[4];
        #pragma unroll
        for (int kc = 0; kc < 4; ++kc) {
            int slot = kc * 4 + quad;
            int boff = crow * 256 + ((slot ^ (crow & 15)) << 4);
            b[kc] = *(const short8*)(bsh + boff);
        }

        floatx4 acc[2] = {{0.f,0.f,0.f,0.f},{0.f,0.f,0.f,0.f}};
        #pragma unroll
        for (int kc = 0; kc < 4; ++kc)
            #pragma unroll
            for (int at = 0; at < 2; ++at)
                acc[at] = __builtin_amdgcn_mfma_f32_16x16x32_bf16(a[at][kc], b[kc], acc[at], 0, 0, 0);

        #pragma unroll
        for (int at = 0; at < 2; ++at)
            #pragma unroll
            for (int r = 0; r < 4; ++r)
                rs[at][r] += fast_exp2(acc[at][r]);
    }

    #pragma unroll
    for (int at = 0; at < 2; ++at) {
        const int gi0 = mbase + at * 16 + quad * 4;
        #pragma unroll
        for (int r = 0; r < 4; ++r) {
            float s = rs[at][r];
            s += __shfl_xor(s, 1);
            s += __shfl_xor(s, 2);
            s += __shfl_xor(s, 4);
            s += __shfl_xor(s, 8);
            if (l15 == 0) psum[(size_t)cs * N2 + gi0 + r] = s;
        }
    }
}

// ---- per-row lse - pos, minus diag term; block-reduce -> atomic loss ------
__global__ __launch_bounds__(256) void row_finalize(
    const unsigned short* __restrict__ Zb, const float* __restrict__ psum,
    float* __restrict__ out)
{
    int i = blockIdx.x * 256 + threadIdx.x;
    float s = 0.f;
    #pragma unroll
    for (int cs = 0; cs < NSPLIT; ++cs) s += psum[(size_t)cs * N2 + i];
    int k = i & (NB - 1);
    const uint4* z1 = (const uint4*)(Zb + (size_t)k * DOUT);
    const uint4* z2 = (const uint4*)(Zb + (size_t)(k + NB) * DOUT);
    float d12 = 0.f, d11 = 0.f, d22 = 0.f;
    #pragma unroll
    for (int q = 0; q < 16; ++q) {
        uint4 a = z1[q], bqq = z2[q];
        const unsigned int aw[4] = {a.x, a.y, a.z, a.w};
        const unsigned int bw[4] = {bqq.x, bqq.y, bqq.z, bqq.w};
        #pragma unroll
        for (int c = 0; c < 4; ++c) {
            float alo = __uint_as_float(aw[c] << 16);
            float ahi = __uint_as_float(aw[c] & 0xffff0000u);
            float blo = __uint_as_float(bw[c] << 16);
            float bhi = __uint_as_float(bw[c] & 0xffff0000u);
            d12 += alo * blo + ahi * bhi;
            d11 += alo * alo + ahi * ahi;
            d22 += blo * blo + bhi * bhi;
        }
    }
    float dself = (i < NB) ? d11 : d22;
    // Zb is scaled: dot' = 2*log2(e)*dot => 2*dot = dot'*ln2; diag = exp2(dot')
    float rowval = logf(s - fast_exp2(dself)) - d12 * 0.69314718f;

    float r = rowval;
    r += __shfl_xor(r, 1);  r += __shfl_xor(r, 2);  r += __shfl_xor(r, 4);
    r += __shfl_xor(r, 8);  r += __shfl_xor(r, 16); r += __shfl_xor(r, 32);
    __shared__ float wsr[4];
    int lane = threadIdx.x & 63, w = threadIdx.x >> 6;
    if (lane == 0) wsr[w] = r;
    __syncthreads();
    if (threadIdx.x == 0)
        atomicAdd(out, (wsr[0] + wsr[1] + wsr[2] + wsr[3]) * (1.0f / N2));
}

extern "C" void kernel_launch(void* const* d_in, const int* in_sizes, int n_in,
                              void* d_out, int out_size, void* d_ws, size_t ws_size,
                              hipStream_t stream)
{
    const float* h1    = (const float*)d_in[0];
    const float* h2    = (const float*)d_in[1];
    const float* W1    = (const float*)d_in[2];
    const float* b1    = (const float*)d_in[3];
    const float* gamma = (const float*)d_in[4];
    const float* beta  = (const float*)d_in[5];
    const float* W2    = (const float*)d_in[6];
    const float* b2    = (const float*)d_in[7];
    float* out = (float*)d_out;

    float* ws      = (float*)d_ws;
    float* psumc   = ws;                            // 1024 f
    float* psqc    = psumc + 1024;                  // 1024 f
    unsigned short* W1b = (unsigned short*)(psqc + 1024);   // 98304 us
    unsigned short* W2b = W1b + DHID * DIN;         // 65536 us
    float* Y       = (float*)(W2b + DOUT * DHID);   // 8192*512 = 4M f (fallback only)
    float* psum    = Y + (size_t)N2 * DHID;         // 32*8192 f
    unsigned short* Zb = (unsigned short*)(psum + (size_t)NSPLIT * N2); // 1M us
    // total ~20.3 MB

    hipMemsetAsync(psumc, 0, 2048 * sizeof(float), stream);  // psumc+psqc
    hipMemsetAsync(out, 0, sizeof(float), stream);           // loss accumulator

    convert_w   <<<dim3(160),        256, 0, stream>>>(W1, W2, W1b, W2b);

    // fused gemm1+BN+gemm2 (cooperative); fallback to split kernels on error
    {
        const unsigned short* W1b_c = W1b;
        const unsigned short* W2b_c = W2b;
        unsigned short* Zb_p = Zb;
        float* outz = out + 1;
        void* args[] = {
            (void*)&h1, (void*)&h2, (void*)&W1b_c, (void*)&b1, (void*)&W2b_c,
            (void*)&psumc, (void*)&psqc, (void*)&gamma, (void*)&beta,
            (void*)&b2, (void*)&Zb_p, (void*)&outz
        };
        hipError_t ce = hipLaunchCooperativeKernel((void*)fused_head,
                                                   dim3(512), dim3(256),
                                                   args, 0, stream);
        if (ce != hipSuccess) {
            gemm1_mfma<<<dim3(64, 8), 256, 0, stream>>>(h1, h2, W1b, b1, Y, psumc, psqc);
            gemm2_mfma<<<dim3(512),   256, 0, stream>>>(Y, W2b, psumc, psqc, gamma, beta, b2, Zb, out + 1);
        }
    }

    sim_mfma    <<<dim3(64, NSPLIT), 256, 0, stream>>>(Zb, psum);
    row_finalize<<<dim3(32),         256, 0, stream>>>(Zb, psum, out);
}

// Round 5
// 141.404 us; speedup vs baseline: 1.5790x; 1.5790x over previous
//
#include <hip/hip_runtime.h>

// SimCLR fused pipeline, round 14.
// r13 post-mortem: cooperative fusion FAILED (87us of barrier spin); but it
// isolated gemm1+gemm2 = ~9us combined. Budget: fill ~42 (harness), sim ~32,
// g1+g2 ~9, convert ~2 -> ~60us unaccounted = dispatch gaps (7 dispatches x
// ~5-10us) + latency-bound row_finalize (32 blocks = 32/256 CUs busy).
// r14 = r12 kernels EXACTLY (gemm1/gemm2/sim untouched) +
//   (a) memsets folded into prep (convert_w + zero psumc/psqc/out): 7->5 disp
//   (b) row_finalize -> one wave per row-PAIR (k,k+NB share d12): 1 uint32
//       per lane per z-row, tree-reduce; 1024 waves over all CUs.

#define NB   4096
#define DIN  192
#define DHID 512
#define DOUT 128
#define N2   8192   // 2*NB
#define NSPLIT 32   // sim col-splits; 256 cols per block
#define SIM_ITERS 16

typedef short short8 __attribute__((ext_vector_type(8)));   // 8 bf16 (4 VGPRs)
typedef float floatx4 __attribute__((ext_vector_type(4)));  // MFMA C/D frag

__device__ inline float fast_exp2(float x) {
#if __has_builtin(__builtin_amdgcn_exp2f)
    return __builtin_amdgcn_exp2f(x);
#else
    return exp2f(x);
#endif
}

__device__ inline unsigned short bf16_rne(float x) {
    unsigned int u = __float_as_uint(x);
    return (unsigned short)((u + 0x7fffu + ((u >> 16) & 1u)) >> 16);
}

// ------- prep: convert W1,W2 -> bf16; block 160 zeros psumc/psqc/out -------
__global__ __launch_bounds__(256) void prep(
    const float* __restrict__ W1, const float* __restrict__ W2,
    unsigned short* __restrict__ W1b, unsigned short* __restrict__ W2b,
    float* __restrict__ psumc, float* __restrict__ psqc, float* __restrict__ out)
{
    const int NW1 = DHID * DIN / 4;   // 24576 float4
    const int NW2 = DOUT * DHID / 4;  // 16384 float4
    if (blockIdx.x == 160) {          // zero accumulators (was 2 hipMemsetAsync)
        int t = threadIdx.x;
        for (int i = t; i < 1024; i += 256) { psumc[i] = 0.f; psqc[i] = 0.f; }
        if (t == 0) out[0] = 0.f;
        return;
    }
    int id = blockIdx.x * 256 + threadIdx.x;
    const float* src; unsigned short* dst; int off;
    if (id < NW1)            { src = W1; dst = W1b; off = id; }
    else if (id < NW1 + NW2) { src = W2; dst = W2b; off = id - NW1; }
    else return;
    float4 x = ((const float4*)src)[off];
    unsigned int p0 = bf16_rne(x.x) | ((unsigned int)bf16_rne(x.y) << 16);
    unsigned int p1 = bf16_rne(x.z) | ((unsigned int)bf16_rne(x.w) << 16);
    ((uint2*)dst)[off] = make_uint2(p0, p1);
}

// ------- GEMM1 (r12, unchanged): Y = [h1;h2] @ W1^T + b1, fused BN sums ----
__global__ __launch_bounds__(256) void gemm1_mfma(
    const float* __restrict__ h1, const float* __restrict__ h2,
    const unsigned short* __restrict__ W1b, const float* __restrict__ b1,
    float* __restrict__ Y, float* __restrict__ psumc, float* __restrict__ psqc)
{
    const int t = threadIdx.x;
    const int wave = t >> 6, lane = t & 63;
    const int quad = lane >> 4, l15 = lane & 15;
    const int mb = blockIdx.x;
    const int m0 = mb * 128 + wave * 32;
    const int n0 = blockIdx.y * 64;
    const int v  = (mb >= 32);

    short8 a[2][6];
    #pragma unroll
    for (int mt = 0; mt < 2; ++mt) {
        int row = m0 + mt * 16 + l15;
        const float* hsrc = (row < NB) ? (h1 + (size_t)row * DIN)
                                       : (h2 + (size_t)(row - NB) * DIN);
        #pragma unroll
        for (int kc = 0; kc < 6; ++kc) {
            const float4* p = (const float4*)(hsrc + kc * 32 + quad * 8);
            float4 x0 = p[0], x1 = p[1];
            float xs[8] = {x0.x,x0.y,x0.z,x0.w,x1.x,x1.y,x1.z,x1.w};
            #pragma unroll
            for (int j = 0; j < 8; ++j) a[mt][kc][j] = (short)bf16_rne(xs[j]);
        }
    }

    #pragma unroll
    for (int nt = 0; nt < 4; ++nt) {
        const int col = n0 + nt * 16 + l15;
        const short8* bptr = (const short8*)(W1b + (size_t)col * DIN + quad * 8);
        short8 b[6];
        #pragma unroll
        for (int kc = 0; kc < 6; ++kc) b[kc] = bptr[kc * 4];
        floatx4 acc[2] = {{0.f,0.f,0.f,0.f},{0.f,0.f,0.f,0.f}};
        #pragma unroll
        for (int kc = 0; kc < 6; ++kc)
            #pragma unroll
            for (int mt = 0; mt < 2; ++mt)
                acc[mt] = __builtin_amdgcn_mfma_f32_16x16x32_bf16(a[mt][kc], b[kc], acc[mt], 0,0,0);
        const float bias = b1[col];
        float cs = 0.f, cq = 0.f;
        #pragma unroll
        for (int mt = 0; mt < 2; ++mt)
            #pragma unroll
            for (int reg = 0; reg < 4; ++reg) {
                float y = acc[mt][reg] + bias;
                int row = m0 + mt * 16 + quad * 4 + reg;
                Y[(size_t)row * DHID + col] = y;
                cs += y; cq += y * y;
            }
        cs += __shfl_xor(cs, 16); cs += __shfl_xor(cs, 32);
        cq += __shfl_xor(cq, 16); cq += __shfl_xor(cq, 32);
        if (quad == 0) {
            atomicAdd(psumc + v * DHID + col, cs);
            atomicAdd(psqc  + v * DHID + col, cq);
        }
    }
}

#define ZSCALE 1.6986436f   // sqrt(2*log2(e)); Zb = z*ZSCALE so dot = exp2 arg

// ---- GEMM2 (r12, unchanged): z = relu(bn(Y)) @ W2^T + b2, L2-norm ---------
__global__ __launch_bounds__(256) void gemm2_mfma(
    const float* __restrict__ Y, const unsigned short* __restrict__ W2b,
    const float* __restrict__ psumc, const float* __restrict__ psqc,
    const float* __restrict__ gamma, const float* __restrict__ beta,
    const float* __restrict__ b2,
    unsigned short* __restrict__ Zb, float* __restrict__ outz)
{
    __shared__ float sc_sh[DHID], sh_sh[DHID];
    __shared__ float sq_lds[4][16];
    const int t = threadIdx.x;
    const int wave = t >> 6, lane = t & 63;
    const int quad = lane >> 4, l15 = lane & 15;
    const int mtbase = blockIdx.x * 16;
    const int v = (mtbase >= NB);

    for (int c = t; c < DHID; c += 256) {
        float mean = psumc[v * DHID + c] * (1.0f / NB);
        float var  = psqc [v * DHID + c] * (1.0f / NB) - mean * mean;
        float rstd = rsqrtf(var + 1e-5f);
        float scv = gamma[c] * rstd;
        sc_sh[c] = scv;
        sh_sh[c] = beta[c] - mean * scv;
    }
    __syncthreads();

    const float* yrow = Y + (size_t)(mtbase + l15) * DHID;
    floatx4 acc[2] = {{0.f,0.f,0.f,0.f},{0.f,0.f,0.f,0.f}};
    for (int kc = 0; kc < 16; ++kc) {
        const int k = kc * 32 + quad * 8;
        float4 y0 = *(const float4*)(yrow + k);
        float4 y1 = *(const float4*)(yrow + k + 4);
        float4 s0 = *(const float4*)&sc_sh[k], s1 = *(const float4*)&sc_sh[k + 4];
        float4 h0 = *(const float4*)&sh_sh[k], h1v = *(const float4*)&sh_sh[k + 4];
        float xs[8];
        xs[0] = fmaxf(y0.x * s0.x + h0.x, 0.f);
        xs[1] = fmaxf(y0.y * s0.y + h0.y, 0.f);
        xs[2] = fmaxf(y0.z * s0.z + h0.z, 0.f);
        xs[3] = fmaxf(y0.w * s0.w + h0.w, 0.f);
        xs[4] = fmaxf(y1.x * s1.x + h1v.x, 0.f);
        xs[5] = fmaxf(y1.y * s1.y + h1v.y, 0.f);
        xs[6] = fmaxf(y1.z * s1.z + h1v.z, 0.f);
        xs[7] = fmaxf(y1.w * s1.w + h1v.w, 0.f);
        short8 a;
        #pragma unroll
        for (int j = 0; j < 8; ++j) a[j] = (short)bf16_rne(xs[j]);
        #pragma unroll
        for (int nt = 0; nt < 2; ++nt) {
            const int col = wave * 32 + nt * 16 + l15;
            short8 b = *(const short8*)(W2b + (size_t)col * DHID + k);
            acc[nt] = __builtin_amdgcn_mfma_f32_16x16x32_bf16(a, b, acc[nt], 0,0,0);
        }
    }
    float bias[2];
    #pragma unroll
    for (int nt = 0; nt < 2; ++nt) bias[nt] = b2[wave * 32 + nt * 16 + l15];

    float zv[4][2];
    #pragma unroll
    for (int reg = 0; reg < 4; ++reg) {
        float sq = 0.f;
        #pragma unroll
        for (int nt = 0; nt < 2; ++nt) {
            zv[reg][nt] = acc[nt][reg] + bias[nt];
            sq += zv[reg][nt] * zv[reg][nt];
        }
        sq += __shfl_xor(sq, 1); sq += __shfl_xor(sq, 2);
        sq += __shfl_xor(sq, 4); sq += __shfl_xor(sq, 8);
        if (l15 == 0) sq_lds[wave][quad * 4 + reg] = sq;
    }
    __syncthreads();
    #pragma unroll
    for (int reg = 0; reg < 4; ++reg) {
        float tot = sq_lds[0][quad * 4 + reg] + sq_lds[1][quad * 4 + reg]
                  + sq_lds[2][quad * 4 + reg] + sq_lds[3][quad * 4 + reg];
        float inv = 1.0f / fmaxf(sqrtf(tot), 1e-12f);
        const int row = mtbase + quad * 4 + reg;
        const size_t ob = (size_t)row * DOUT;
        #pragma unroll
        for (int nt = 0; nt < 2; ++nt) {
            const int col = wave * 32 + nt * 16 + l15;
            float z = zv[reg][nt] * inv;
            outz[ob + col] = z;
            Zb[ob + col] = bf16_rne(z * ZSCALE);
        }
    }
}

// ---- sim (r12, unchanged): psum_row = sum_cols exp2(Zb . Zb^T) ------------
__global__ __launch_bounds__(256, 2) void sim_mfma(
    const unsigned short* __restrict__ Zb, float* __restrict__ psum)
{
    __shared__ unsigned char bsh[65536];   // 256 rows x 256 B, swizzled
    const int t = threadIdx.x;
    const int wave = t >> 6, lane = t & 63;
    const int quad = lane >> 4, l15 = lane & 15;
    const int mbase = blockIdx.x * 128 + wave * 32;   // 32 rows per wave
    const int cs = blockIdx.y;                        // 0..NSPLIT-1
    const int cbase = cs * (N2 / NSPLIT);             // 256-col slice

    {
        const uint4* src = (const uint4*)(Zb + (size_t)cbase * DOUT);
        #pragma unroll
        for (int k = 0; k < 16; ++k) {
            int idx = t + k * 256;            // uint4 index 0..4095
            uint4 vv = src[idx];
            int row  = idx >> 4;              // slice row 0..255
            int slot = idx & 15;              // 16B slot within row
            *(uint4*)(bsh + row * 256 + ((slot ^ (row & 15)) << 4)) = vv;
        }
    }

    short8 a[2][4];
    #pragma unroll
    for (int at = 0; at < 2; ++at) {
        const short8* zra = (const short8*)(Zb + (size_t)(mbase + at * 16 + l15) * DOUT + quad * 8);
        #pragma unroll
        for (int kc = 0; kc < 4; ++kc) a[at][kc] = zra[kc * 4];
    }

    float rs[2][4];
    #pragma unroll
    for (int at = 0; at < 2; ++at)
        #pragma unroll
        for (int r = 0; r < 4; ++r) rs[at][r] = 0.f;

    __syncthreads();   // B slice staged

    #pragma unroll 1
    for (int nt = 0; nt < SIM_ITERS; ++nt) {
        const int crow = nt * 16 + l15;
        short8 b[4];
        #pragma unroll
        for (int kc = 0; kc < 4; ++kc) {
            int slot = kc * 4 + quad;
            int boff = crow * 256 + ((slot ^ (crow & 15)) << 4);
            b[kc] = *(const short8*)(bsh + boff);
        }

        floatx4 acc[2] = {{0.f,0.f,0.f,0.f},{0.f,0.f,0.f,0.f}};
        #pragma unroll
        for (int kc = 0; kc < 4; ++kc)
            #pragma unroll
            for (int at = 0; at < 2; ++at)
                acc[at] = __builtin_amdgcn_mfma_f32_16x16x32_bf16(a[at][kc], b[kc], acc[at], 0, 0, 0);

        #pragma unroll
        for (int at = 0; at < 2; ++at)
            #pragma unroll
            for (int r = 0; r < 4; ++r)
                rs[at][r] += fast_exp2(acc[at][r]);
    }

    #pragma unroll
    for (int at = 0; at < 2; ++at) {
        const int gi0 = mbase + at * 16 + quad * 4;
        #pragma unroll
        for (int r = 0; r < 4; ++r) {
            float s = rs[at][r];
            s += __shfl_xor(s, 1);
            s += __shfl_xor(s, 2);
            s += __shfl_xor(s, 4);
            s += __shfl_xor(s, 8);
            if (l15 == 0) psum[(size_t)cs * N2 + gi0 + r] = s;
        }
    }
}

// ---- row_finalize v2: one WAVE per row-pair (k, k+NB) ---------------------
// z-row = 128 bf16 = 64 uint32 = exactly 1 uint32/lane (coalesced 256B).
// d11/d12/d22 via 6-step tree reduce; psum slices: lanes 0..31 -> row k,
// lanes 32..63 -> row k+NB (1 load/lane, 5-step half-reduce).
// grid 256 x 256 thr = 1024 waves, 4 pairs each.
__global__ __launch_bounds__(256) void row_finalize(
    const unsigned short* __restrict__ Zb, const float* __restrict__ psum,
    float* __restrict__ out)
{
    const int t = threadIdx.x, wave = t >> 6, lane = t & 63;
    const int half = lane >> 5, l5 = lane & 31;
    const unsigned int* Z32 = (const unsigned int*)Zb;
    const int gw = blockIdx.x * 4 + wave;   // 0..1023
    float accrv = 0.f;

    #pragma unroll 1
    for (int pp = 0; pp < 4; ++pp) {
        const int k = gw * 4 + pp;          // pair 0..4095
        // psum partial: half 0 -> row k, half 1 -> row k+NB
        float s = psum[(size_t)l5 * N2 + k + half * NB];
        s += __shfl_xor(s, 1); s += __shfl_xor(s, 2); s += __shfl_xor(s, 4);
        s += __shfl_xor(s, 8); s += __shfl_xor(s, 16);
        // dot products: full-wave tree
        unsigned int aw = Z32[(size_t)k * 64 + lane];
        unsigned int bw = Z32[(size_t)(k + NB) * 64 + lane];
        float alo = __uint_as_float(aw << 16), ahi = __uint_as_float(aw & 0xffff0000u);
        float blo = __uint_as_float(bw << 16), bhi = __uint_as_float(bw & 0xffff0000u);
        float d12 = alo * blo + ahi * bhi;
        float d11 = alo * alo + ahi * ahi;
        float d22 = blo * blo + bhi * bhi;
        #pragma unroll
        for (int m = 1; m <= 32; m <<= 1) {
            d12 += __shfl_xor(d12, m);
            d11 += __shfl_xor(d11, m);
            d22 += __shfl_xor(d22, m);
        }
        // Zb scaled: dot' = 2*log2(e)*dot; diag = exp2(dself'); pos = d12'*ln2/... 
        if (l5 == 0) {
            float dself = half ? d22 : d11;
            accrv += logf(s - fast_exp2(dself)) - d12 * 0.69314718f;
        }
    }
    accrv += __shfl_xor(accrv, 32);   // lane0 += lane32 contribution
    __shared__ float wsr[4];
    if (lane == 0) wsr[wave] = accrv;
    __syncthreads();
    if (t == 0)
        atomicAdd(out, (wsr[0] + wsr[1] + wsr[2] + wsr[3]) * (1.0f / N2));
}

extern "C" void kernel_launch(void* const* d_in, const int* in_sizes, int n_in,
                              void* d_out, int out_size, void* d_ws, size_t ws_size,
                              hipStream_t stream)
{
    const float* h1    = (const float*)d_in[0];
    const float* h2    = (const float*)d_in[1];
    const float* W1    = (const float*)d_in[2];
    const float* b1    = (const float*)d_in[3];
    const float* gamma = (const float*)d_in[4];
    const float* beta  = (const float*)d_in[5];
    const float* W2    = (const float*)d_in[6];
    const float* b2    = (const float*)d_in[7];
    float* out = (float*)d_out;

    float* ws      = (float*)d_ws;
    float* psumc   = ws;                            // 1024 f
    float* psqc    = psumc + 1024;                  // 1024 f
    unsigned short* W1b = (unsigned short*)(psqc + 1024);   // 98304 us
    unsigned short* W2b = W1b + DHID * DIN;         // 65536 us
    float* Y       = (float*)(W2b + DOUT * DHID);   // 8192*512 = 4M f
    float* psum    = Y + (size_t)N2 * DHID;         // 32*8192 f
    unsigned short* Zb = (unsigned short*)(psum + (size_t)NSPLIT * N2); // 1M us
    // total ~20.3 MB

    prep        <<<dim3(161),        256, 0, stream>>>(W1, W2, W1b, W2b, psumc, psqc, out);
    gemm1_mfma  <<<dim3(64, 8),      256, 0, stream>>>(h1, h2, W1b, b1, Y, psumc, psqc);
    gemm2_mfma  <<<dim3(512),        256, 0, stream>>>(Y, W2b, psumc, psqc, gamma, beta, b2, Zb, out + 1);
    sim_mfma    <<<dim3(64, NSPLIT), 256, 0, stream>>>(Zb, psum);
    row_finalize<<<dim3(256),        256, 0, stream>>>(Zb, psum, out);
}

// Round 6
// 141.163 us; speedup vs baseline: 1.5817x; 1.0017x over previous
//
#include <hip/hip_runtime.h>

// SimCLR fused pipeline, round 15.
// r14 post-mortem: dur_us = sum(kernel durs) + ~97us harness constant (the
// 268MB workspace-poison fills, 42us each, are IN the timed region).
// Controllable: prep ~2 + g1/g2 ~9 + sim ~30 + rowfin ~2.
// r15 change: sim exploits symmetry of S = Z.Z^T. 256x256 super-block upper
// triangle only: 32 diag supers (row-sums only) + 496 strict-upper supers
// (row-sums AND col-sums -- each exp serves rows i and j). Blocks 2048->1056.
// Col-sum via lane-local add + shfl_xor(16,32) + per-wave LDS acc + one
// global atomicAdd per col per block. psum -> atomic psum_row[8192] (zeroed
// in prep); row_finalize reads 1 value instead of 32-slice reduce.
// gemm1/gemm2 (r12) untouched.

#define NB   4096
#define DIN  192
#define DHID 512
#define DOUT 128
#define N2   8192   // 2*NB
#define NSUPER 32   // 256-row super-blocks
#define SIM_ITERS 16

typedef short short8 __attribute__((ext_vector_type(8)));   // 8 bf16 (4 VGPRs)
typedef float floatx4 __attribute__((ext_vector_type(4)));  // MFMA C/D frag

__device__ inline float fast_exp2(float x) {
#if __has_builtin(__builtin_amdgcn_exp2f)
    return __builtin_amdgcn_exp2f(x);
#else
    return exp2f(x);
#endif
}

__device__ inline unsigned short bf16_rne(float x) {
    unsigned int u = __float_as_uint(x);
    return (unsigned short)((u + 0x7fffu + ((u >> 16) & 1u)) >> 16);
}

// ------- prep: convert W1,W2 -> bf16; block 160 zeros accumulators ---------
__global__ __launch_bounds__(256) void prep(
    const float* __restrict__ W1, const float* __restrict__ W2,
    unsigned short* __restrict__ W1b, unsigned short* __restrict__ W2b,
    float* __restrict__ psumc, float* __restrict__ psqc,
    float* __restrict__ out, float* __restrict__ psum_row)
{
    const int NW1 = DHID * DIN / 4;   // 24576 float4
    const int NW2 = DOUT * DHID / 4;  // 16384 float4
    if (blockIdx.x == 160) {          // zero accumulators
        int t = threadIdx.x;
        for (int i = t; i < 1024; i += 256) { psumc[i] = 0.f; psqc[i] = 0.f; }
        for (int i = t; i < N2; i += 256)   psum_row[i] = 0.f;
        if (t == 0) out[0] = 0.f;
        return;
    }
    int id = blockIdx.x * 256 + threadIdx.x;
    const float* src; unsigned short* dst; int off;
    if (id < NW1)            { src = W1; dst = W1b; off = id; }
    else if (id < NW1 + NW2) { src = W2; dst = W2b; off = id - NW1; }
    else return;
    float4 x = ((const float4*)src)[off];
    unsigned int p0 = bf16_rne(x.x) | ((unsigned int)bf16_rne(x.y) << 16);
    unsigned int p1 = bf16_rne(x.z) | ((unsigned int)bf16_rne(x.w) << 16);
    ((uint2*)dst)[off] = make_uint2(p0, p1);
}

// ------- GEMM1 (r12, unchanged): Y = [h1;h2] @ W1^T + b1, fused BN sums ----
__global__ __launch_bounds__(256) void gemm1_mfma(
    const float* __restrict__ h1, const float* __restrict__ h2,
    const unsigned short* __restrict__ W1b, const float* __restrict__ b1,
    float* __restrict__ Y, float* __restrict__ psumc, float* __restrict__ psqc)
{
    const int t = threadIdx.x;
    const int wave = t >> 6, lane = t & 63;
    const int quad = lane >> 4, l15 = lane & 15;
    const int mb = blockIdx.x;
    const int m0 = mb * 128 + wave * 32;
    const int n0 = blockIdx.y * 64;
    const int v  = (mb >= 32);

    short8 a[2][6];
    #pragma unroll
    for (int mt = 0; mt < 2; ++mt) {
        int row = m0 + mt * 16 + l15;
        const float* hsrc = (row < NB) ? (h1 + (size_t)row * DIN)
                                       : (h2 + (size_t)(row - NB) * DIN);
        #pragma unroll
        for (int kc = 0; kc < 6; ++kc) {
            const float4* p = (const float4*)(hsrc + kc * 32 + quad * 8);
            float4 x0 = p[0], x1 = p[1];
            float xs[8] = {x0.x,x0.y,x0.z,x0.w,x1.x,x1.y,x1.z,x1.w};
            #pragma unroll
            for (int j = 0; j < 8; ++j) a[mt][kc][j] = (short)bf16_rne(xs[j]);
        }
    }

    #pragma unroll
    for (int nt = 0; nt < 4; ++nt) {
        const int col = n0 + nt * 16 + l15;
        const short8* bptr = (const short8*)(W1b + (size_t)col * DIN + quad * 8);
        short8 b[6];
        #pragma unroll
        for (int kc = 0; kc < 6; ++kc) b[kc] = bptr[kc * 4];
        floatx4 acc[2] = {{0.f,0.f,0.f,0.f},{0.f,0.f,0.f,0.f}};
        #pragma unroll
        for (int kc = 0; kc < 6; ++kc)
            #pragma unroll
            for (int mt = 0; mt < 2; ++mt)
                acc[mt] = __builtin_amdgcn_mfma_f32_16x16x32_bf16(a[mt][kc], b[kc], acc[mt], 0,0,0);
        const float bias = b1[col];
        float cs = 0.f, cq = 0.f;
        #pragma unroll
        for (int mt = 0; mt < 2; ++mt)
            #pragma unroll
            for (int reg = 0; reg < 4; ++reg) {
                float y = acc[mt][reg] + bias;
                int row = m0 + mt * 16 + quad * 4 + reg;
                Y[(size_t)row * DHID + col] = y;
                cs += y; cq += y * y;
            }
        cs += __shfl_xor(cs, 16); cs += __shfl_xor(cs, 32);
        cq += __shfl_xor(cq, 16); cq += __shfl_xor(cq, 32);
        if (quad == 0) {
            atomicAdd(psumc + v * DHID + col, cs);
            atomicAdd(psqc  + v * DHID + col, cq);
        }
    }
}

#define ZSCALE 1.6986436f   // sqrt(2*log2(e)); Zb = z*ZSCALE so dot = exp2 arg

// ---- GEMM2 (r12, unchanged): z = relu(bn(Y)) @ W2^T + b2, L2-norm ---------
__global__ __launch_bounds__(256) void gemm2_mfma(
    const float* __restrict__ Y, const unsigned short* __restrict__ W2b,
    const float* __restrict__ psumc, const float* __restrict__ psqc,
    const float* __restrict__ gamma, const float* __restrict__ beta,
    const float* __restrict__ b2,
    unsigned short* __restrict__ Zb, float* __restrict__ outz)
{
    __shared__ float sc_sh[DHID], sh_sh[DHID];
    __shared__ float sq_lds[4][16];
    const int t = threadIdx.x;
    const int wave = t >> 6, lane = t & 63;
    const int quad = lane >> 4, l15 = lane & 15;
    const int mtbase = blockIdx.x * 16;
    const int v = (mtbase >= NB);

    for (int c = t; c < DHID; c += 256) {
        float mean = psumc[v * DHID + c] * (1.0f / NB);
        float var  = psqc [v * DHID + c] * (1.0f / NB) - mean * mean;
        float rstd = rsqrtf(var + 1e-5f);
        float scv = gamma[c] * rstd;
        sc_sh[c] = scv;
        sh_sh[c] = beta[c] - mean * scv;
    }
    __syncthreads();

    const float* yrow = Y + (size_t)(mtbase + l15) * DHID;
    floatx4 acc[2] = {{0.f,0.f,0.f,0.f},{0.f,0.f,0.f,0.f}};
    for (int kc = 0; kc < 16; ++kc) {
        const int k = kc * 32 + quad * 8;
        float4 y0 = *(const float4*)(yrow + k);
        float4 y1 = *(const float4*)(yrow + k + 4);
        float4 s0 = *(const float4*)&sc_sh[k], s1 = *(const float4*)&sc_sh[k + 4];
        float4 h0 = *(const float4*)&sh_sh[k], h1v = *(const float4*)&sh_sh[k + 4];
        float xs[8];
        xs[0] = fmaxf(y0.x * s0.x + h0.x, 0.f);
        xs[1] = fmaxf(y0.y * s0.y + h0.y, 0.f);
        xs[2] = fmaxf(y0.z * s0.z + h0.z, 0.f);
        xs[3] = fmaxf(y0.w * s0.w + h0.w, 0.f);
        xs[4] = fmaxf(y1.x * s1.x + h1v.x, 0.f);
        xs[5] = fmaxf(y1.y * s1.y + h1v.y, 0.f);
        xs[6] = fmaxf(y1.z * s1.z + h1v.z, 0.f);
        xs[7] = fmaxf(y1.w * s1.w + h1v.w, 0.f);
        short8 a;
        #pragma unroll
        for (int j = 0; j < 8; ++j) a[j] = (short)bf16_rne(xs[j]);
        #pragma unroll
        for (int nt = 0; nt < 2; ++nt) {
            const int col = wave * 32 + nt * 16 + l15;
            short8 b = *(const short8*)(W2b + (size_t)col * DHID + k);
            acc[nt] = __builtin_amdgcn_mfma_f32_16x16x32_bf16(a, b, acc[nt], 0,0,0);
        }
    }
    float bias[2];
    #pragma unroll
    for (int nt = 0; nt < 2; ++nt) bias[nt] = b2[wave * 32 + nt * 16 + l15];

    float zv[4][2];
    #pragma unroll
    for (int reg = 0; reg < 4; ++reg) {
        float sq = 0.f;
        #pragma unroll
        for (int nt = 0; nt < 2; ++nt) {
            zv[reg][nt] = acc[nt][reg] + bias[nt];
            sq += zv[reg][nt] * zv[reg][nt];
        }
        sq += __shfl_xor(sq, 1); sq += __shfl_xor(sq, 2);
        sq += __shfl_xor(sq, 4); sq += __shfl_xor(sq, 8);
        if (l15 == 0) sq_lds[wave][quad * 4 + reg] = sq;
    }
    __syncthreads();
    #pragma unroll
    for (int reg = 0; reg < 4; ++reg) {
        float tot = sq_lds[0][quad * 4 + reg] + sq_lds[1][quad * 4 + reg]
                  + sq_lds[2][quad * 4 + reg] + sq_lds[3][quad * 4 + reg];
        float inv = 1.0f / fmaxf(sqrtf(tot), 1e-12f);
        const int row = mtbase + quad * 4 + reg;
        const size_t ob = (size_t)row * DOUT;
        #pragma unroll
        for (int nt = 0; nt < 2; ++nt) {
            const int col = wave * 32 + nt * 16 + l15;
            float z = zv[reg][nt] * inv;
            outz[ob + col] = z;
            Zb[ob + col] = bf16_rne(z * ZSCALE);
        }
    }
}

// ---- sim v3 (symmetric): upper-triangle 256x256 super-blocks --------------
// Block = 128 rows x 256 cols (half super-row). id<64: diagonal supers
// (C==R, row-sums only). Else strict-upper (C>R): row-sums AND col-sums
// (exp(S[i][j]) also feeds row j via symmetry). B slice LDS-staged (r12
// swizzle); A frags in regs (32 rows/wave). psum_row accumulated atomically.
__global__ __launch_bounds__(256, 2) void sim_mfma(
    const unsigned short* __restrict__ Zb, float* __restrict__ psum_row)
{
    __shared__ unsigned char bsh[65536];   // 256 rows x 256 B, swizzled
    __shared__ float colsum[4][256];
    const int t = threadIdx.x;
    const int wave = t >> 6, lane = t & 63;
    const int quad = lane >> 4, l15 = lane & 15;

    // ---- decode blockIdx -> (R, C, half) ----
    int R, C, half;
    {
        int id = blockIdx.x;
        if (id < 2 * NSUPER) { R = id >> 1; C = R; half = id & 1; }
        else {
            int p2 = id - 2 * NSUPER;
            int pair = p2 >> 1; half = p2 & 1;
            int r = 0, rem = pair;
            while (rem >= NSUPER - 1 - r) { rem -= NSUPER - 1 - r; ++r; }
            R = r; C = r + 1 + rem;
        }
    }
    const bool docol = (C != R);
    const int mbase = R * 256 + half * 128 + wave * 32;
    const int cbase = C * 256;

    // ---- stage B slice into LDS (swizzled), zero colsum ----
    {
        const uint4* src = (const uint4*)(Zb + (size_t)cbase * DOUT);
        #pragma unroll
        for (int k = 0; k < 16; ++k) {
            int idx = t + k * 256;            // uint4 index 0..4095
            uint4 vv = src[idx];
            int row  = idx >> 4;              // slice row 0..255
            int slot = idx & 15;              // 16B slot within row
            *(uint4*)(bsh + row * 256 + ((slot ^ (row & 15)) << 4)) = vv;
        }
        #pragma unroll
        for (int w = 0; w < 4; ++w) colsum[w][t] = 0.f;
    }

    // A fragments: 32 rows per wave, K=128 (4 kc)
    short8 a[2][4];
    #pragma unroll
    for (int at = 0; at < 2; ++at) {
        const short8* zra = (const short8*)(Zb + (size_t)(mbase + at * 16 + l15) * DOUT + quad * 8);
        #pragma unroll
        for (int kc = 0; kc < 4; ++kc) a[at][kc] = zra[kc * 4];
    }

    float rs[2][4];
    #pragma unroll
    for (int at = 0; at < 2; ++at)
        #pragma unroll
        for (int r = 0; r < 4; ++r) rs[at][r] = 0.f;

    __syncthreads();   // B slice staged, colsum zeroed

    #pragma unroll 1
    for (int nt = 0; nt < SIM_ITERS; ++nt) {
        const int crow = nt * 16 + l15;
        short8 b[4];
        #pragma unroll
        for (int kc = 0; kc < 4; ++kc) {
            int slot = kc * 4 + quad;
            int boff = crow * 256 + ((slot ^ (crow & 15)) << 4);
            b[kc] = *(const short8*)(bsh + boff);
        }

        floatx4 acc[2] = {{0.f,0.f,0.f,0.f},{0.f,0.f,0.f,0.f}};
        #pragma unroll
        for (int kc = 0; kc < 4; ++kc)
            #pragma unroll
            for (int at = 0; at < 2; ++at)
                acc[at] = __builtin_amdgcn_mfma_f32_16x16x32_bf16(a[at][kc], b[kc], acc[at], 0, 0, 0);

        float cst = 0.f;
        #pragma unroll
        for (int at = 0; at < 2; ++at)
            #pragma unroll
            for (int r = 0; r < 4; ++r) {
                float e = fast_exp2(acc[at][r]);
                rs[at][r] += e;
                cst += e;
            }
        if (docol) {
            // col l15 of this c-tile: sum over the wave's 32 m-rows
            cst += __shfl_xor(cst, 16);
            cst += __shfl_xor(cst, 32);
            if (quad == 0) colsum[wave][nt * 16 + l15] += cst;
        }
    }

    __syncthreads();   // colsum complete

    // row-sums -> atomic psum_row
    #pragma unroll
    for (int at = 0; at < 2; ++at) {
        const int gi0 = mbase + at * 16 + quad * 4;
        #pragma unroll
        for (int r = 0; r < 4; ++r) {
            float s = rs[at][r];
            s += __shfl_xor(s, 1);
            s += __shfl_xor(s, 2);
            s += __shfl_xor(s, 4);
            s += __shfl_xor(s, 8);
            if (l15 == 0) atomicAdd(psum_row + gi0 + r, s);
        }
    }
    // col-sums -> atomic psum_row (strict-upper blocks only)
    if (docol) {
        float tot = colsum[0][t] + colsum[1][t] + colsum[2][t] + colsum[3][t];
        atomicAdd(psum_row + cbase + t, tot);
    }
}

// ---- row_finalize v3: one wave per row-pair; psum_row is a single load ----
__global__ __launch_bounds__(256) void row_finalize(
    const unsigned short* __restrict__ Zb, const float* __restrict__ psum_row,
    float* __restrict__ out)
{
    const int t = threadIdx.x, wave = t >> 6, lane = t & 63;
    const int half = lane >> 5, l5 = lane & 31;
    const unsigned int* Z32 = (const unsigned int*)Zb;
    const int gw = blockIdx.x * 4 + wave;   // 0..1023
    float accrv = 0.f;

    #pragma unroll 1
    for (int pp = 0; pp < 4; ++pp) {
        const int k = gw * 4 + pp;          // pair 0..4095
        unsigned int aw = Z32[(size_t)k * 64 + lane];
        unsigned int bw = Z32[(size_t)(k + NB) * 64 + lane];
        float alo = __uint_as_float(aw << 16), ahi = __uint_as_float(aw & 0xffff0000u);
        float blo = __uint_as_float(bw << 16), bhi = __uint_as_float(bw & 0xffff0000u);
        float d12 = alo * blo + ahi * bhi;
        float d11 = alo * alo + ahi * ahi;
        float d22 = blo * blo + bhi * bhi;
        #pragma unroll
        for (int m = 1; m <= 32; m <<= 1) {
            d12 += __shfl_xor(d12, m);
            d11 += __shfl_xor(d11, m);
            d22 += __shfl_xor(d22, m);
        }
        if (l5 == 0) {
            float s = psum_row[k + half * NB];
            float dself = half ? d22 : d11;
            accrv += logf(s - fast_exp2(dself)) - d12 * 0.69314718f;
        }
    }
    accrv += __shfl_xor(accrv, 32);   // lane0 += lane32 contribution
    __shared__ float wsr[4];
    if (lane == 0) wsr[wave] = accrv;
    __syncthreads();
    if (t == 0)
        atomicAdd(out, (wsr[0] + wsr[1] + wsr[2] + wsr[3]) * (1.0f / N2));
}

extern "C" void kernel_launch(void* const* d_in, const int* in_sizes, int n_in,
                              void* d_out, int out_size, void* d_ws, size_t ws_size,
                              hipStream_t stream)
{
    const float* h1    = (const float*)d_in[0];
    const float* h2    = (const float*)d_in[1];
    const float* W1    = (const float*)d_in[2];
    const float* b1    = (const float*)d_in[3];
    const float* gamma = (const float*)d_in[4];
    const float* beta  = (const float*)d_in[5];
    const float* W2    = (const float*)d_in[6];
    const float* b2    = (const float*)d_in[7];
    float* out = (float*)d_out;

    float* ws      = (float*)d_ws;
    float* psumc   = ws;                            // 1024 f
    float* psqc    = psumc + 1024;                  // 1024 f
    unsigned short* W1b = (unsigned short*)(psqc + 1024);   // 98304 us
    unsigned short* W2b = W1b + DHID * DIN;         // 65536 us
    float* Y       = (float*)(W2b + DOUT * DHID);   // 8192*512 = 4M f
    float* psum_row= Y + (size_t)N2 * DHID;         // 8192 f (atomic row sums)
    unsigned short* Zb = (unsigned short*)(psum_row + N2); // 1M us
    // total ~19.4 MB

    // sim grid: 64 diag half-blocks + 992 strict-upper half-blocks
    const int SIM_BLOCKS = 2 * NSUPER + (NSUPER * (NSUPER - 1) / 2) * 2;  // 1056

    prep        <<<dim3(161),        256, 0, stream>>>(W1, W2, W1b, W2b, psumc, psqc, out, psum_row);
    gemm1_mfma  <<<dim3(64, 8),      256, 0, stream>>>(h1, h2, W1b, b1, Y, psumc, psqc);
    gemm2_mfma  <<<dim3(512),        256, 0, stream>>>(Y, W2b, psumc, psqc, gamma, beta, b2, Zb, out + 1);
    sim_mfma    <<<dim3(SIM_BLOCKS), 256, 0, stream>>>(Zb, psum_row);
    row_finalize<<<dim3(256),        256, 0, stream>>>(Zb, psum_row, out);
}